// Round 12
// baseline (108.089 us; speedup 1.0000x reference)
//
#include <hip/hip_runtime.h>
#include <math.h>

// MutualInformationLoss on MI355X — round 20.
// r19 (99.7us): per-batch finalize fixed the downstream; K1 (42.9us) is the
// remaining target. r12: LDS pipe is OP-bound. r14-18: tr-read path closed.
// This round: keep [bin][vox] layout + proven b128 fragment reads; make the
// WRITES op-minimal. Lane owns 2 adjacent voxel columns (chunk=128 vox/wave):
// (row r, cols 2l,2l+1) = one aligned dword -> full 23-row column-pair
// written as packed dwords via ds_write2_b32 (2 rows/instr):
//   12 write instr/image, NO zeroing (every row written every chunk; values
//   are w or exact 0 from the r16-HW-validated per-quad factorization).
// DS ops per 128 vox: 58 -> 40; data-dependent scatter conflicts vanish.
// Row stride 136 halves (68 dwords = 4 mod 32: same bank pattern as RS=72).
// VALU ~2.2x (full 23-bin windows + packing) — slack at 15.5% busy.
// LDS 12.5KB/wave -> 3 blocks/CU (r11: kernel is pipe-bound, not occupancy).
// asm writes have no dest regs (immune to r17 spill-NaN class); write->read
// ordering = same-wave in-order DS (baseline already relies on it).
// Downstream: r19 per-batch-finalize K2, unchanged.

#define NBINS   23
#define NCELLS  529
#define NBATCH  4
#define NVOX    884736
#define PBLK    432               // K1 blocks per batch: 432 * 2048 = 884736
#define RPB     16                // partial rows per reduce block (432/27)
#define RBLK    (PBLK / RPB)      // 27
#define RSH     136               // row stride in halves (272 B, 68 dwords)
#define RSB     272
#define IMG4    (23 * RSB)        // 6256 B per image (rows 0..22, 128 cols)
#define WREG    (2 * IMG4)        // 12512 B per wave (A + B images)
#define SMEMB   (4 * WREG + 2496) // 52544 B: guard covers m>=23 B-img reads
                                  // (max 52480); 3 blocks/CU (157632<=160K)

typedef float    vf2  __attribute__((ext_vector_type(2)));
typedef _Float16 h2t  __attribute__((ext_vector_type(2)));
typedef _Float16 h8   __attribute__((ext_vector_type(8)));
typedef float    f16v __attribute__((ext_vector_type(16)));

#define G1 0.13533528f        // exp(-2)
#define G2 3.3546263e-4f      // exp(-8)
#define G3 1.5229979e-8f      // exp(-18)

// paired-row LDS write: 2 dwords at vaddr + {O0,O1} dwords
#define DSW2(A, LO, HI, O0, O1)                                         \
    asm volatile("ds_write2_b32 %0, %1, %2 offset0:" #O0 " offset1:" #O1 \
                 :: "v"(A), "v"(LO), "v"(HI) : "memory")

// Full 23-bin Parzen window, branch-free, per-quad factorization
// (r16 HW-validated): quad q at base 4q: vq = x - 4q/22,
// W0 = exp(-968 vq^2), R = exp(88 vq) (<= e^88, finite in f32),
// w[4q+t] = W0*R^t*G(t); p-chain values are shifted Gaussians <= e^18.
// Far quads underflow W0 to exact 0 (0 * finite = 0). Returns sum w[0..22].
__device__ __forceinline__ float window23(float x, float* w)
{
    x = fminf(fmaxf(x, 0.0f), 1.0f);
    #pragma unroll
    for (int q = 0; q < 6; ++q) {
        float vq = fmaf((float)(4 * q), -(1.0f / 22.0f), x);
        float W0 = __expf(-968.0f * (vq * vq));
        float R  = __expf(88.0f * vq);
        float p  = W0;
        w[4 * q] = p;
        p *= R;  w[4 * q + 1] = p * G1;
        p *= R;  w[4 * q + 2] = p * G2;
        if (q < 5) { p *= R; w[4 * q + 3] = p * G3; }
    }
    float s0 = ((w[0] + w[1]) + (w[2] + w[3])) + ((w[4] + w[5]) + (w[6] + w[7]));
    float s1 = ((w[8] + w[9]) + (w[10] + w[11]))
             + ((w[12] + w[13]) + (w[14] + w[15]));
    float s2 = ((w[16] + w[17]) + (w[18] + w[19])) + ((w[20] + w[21]) + w[22]);
    return (s0 + s1) + s2;
}

// pack two f32 -> one dword of 2 f16 (RNE casts; col 2l = low half)
__device__ __forceinline__ unsigned int pk(float a, float b)
{
    h2t t; t[0] = (_Float16)a; t[1] = (_Float16)b;
    return __builtin_bit_cast(unsigned int, t);
}

// ---------------- K1: fused Parzen-window + MFMA joint histogram ----------------
__global__ __launch_bounds__(256, 3)
void mi_mfma(const float* __restrict__ pred,
             const float* __restrict__ targ,
             float* __restrict__ partial,      // [NBATCH*PBLK][NCELLS]
             double* __restrict__ pab64,       // zeroed here for K2
             int* __restrict__ cnt)            // [5], zeroed here for K2
{
    __shared__ __align__(16) char smem[SMEMB];

    // Block (0,0) zeroes K2's accumulators + counters (replaces memset;
    // K2 runs after K1 completes in stream order, so no race).
    if (blockIdx.x == 0 && blockIdx.y == 0) {
        for (int c = threadIdx.x; c < NBATCH * NCELLS; c += 256)
            pab64[c] = 0.0;
        if (threadIdx.x < 5) cnt[threadIdx.x] = 0;
    }

    const int p    = blockIdx.x;
    const int b    = blockIdx.y;
    const int wv   = threadIdx.x >> 6;
    const int lane = threadIdx.x & 63;
    const int m    = lane & 31;               // bin row for fragment reads
    const int h    = lane >> 5;               // k-half selector

    char* wbase = smem + wv * WREG;
    const _Float16* AimgH = (const _Float16*)wbase;
    const _Float16* BimgH = (const _Float16*)(wbase + IMG4);

    // write bases: (row r, col 2l) byte = r*272 + 4l; group g = rows 4g..4g+3
    const unsigned int awA = (unsigned int)(uintptr_t)wbase + 4u * lane;
    const unsigned int awB = awA + IMG4;

    // lane owns voxels 2l, 2l+1 of each 128-voxel chunk (4 chunks/wave)
    const size_t base2 = (size_t)b * NVOX + (size_t)p * 2048
                       + (size_t)wv * 512 + 2 * (size_t)lane;

    f16v acc = {};

    #pragma unroll 1
    for (int c = 0; c < 4; ++c) {
        vf2 xv = *(const vf2*)(pred + base2 + (size_t)c * 128);
        vf2 yv = *(const vf2*)(targ + base2 + (size_t)c * 128);

        float wx0[23], wx1[23], wy0[23], wy1[23];
        float sx0 = window23(xv.x, wx0);
        float sx1 = window23(xv.y, wx1);
        float sy0 = window23(yv.x, wy0);
        float sy1 = window23(yv.y, wy1);
        float i0 = __builtin_amdgcn_rcpf(sx0 * sy0);  // fold both norms on A
        float i1 = __builtin_amdgcn_rcpf(sx1 * sy1);

        unsigned int dA[23], dB[23];
        #pragma unroll
        for (int r = 0; r < 23; ++r) {
            dA[r] = pk(wx0[r] * i0, wx1[r] * i1);
            dB[r] = pk(wy0[r], wy1[r]);
        }

        // full-column writes: 11 write2 + 1 b32 per image (rows 0..22).
        // offsets in dwords (row stride 68); vaddr stepped 1088 B / 4 rows.
        #pragma unroll
        for (int gg = 0; gg < 5; ++gg) {
            unsigned int aA = awA + gg * 1088u, aB = awB + gg * 1088u;
            DSW2(aA, dA[4 * gg],     dA[4 * gg + 1], 0, 68);
            DSW2(aA, dA[4 * gg + 2], dA[4 * gg + 3], 136, 204);
            DSW2(aB, dB[4 * gg],     dB[4 * gg + 1], 0, 68);
            DSW2(aB, dB[4 * gg + 2], dB[4 * gg + 3], 136, 204);
        }
        {
            unsigned int aA = awA + 5u * 1088u, aB = awB + 5u * 1088u;
            DSW2(aA, dA[20], dA[21], 0, 68);
            DSW2(aB, dB[20], dB[21], 0, 68);
            asm volatile("ds_write_b32 %0, %1 offset:544"
                         :: "v"(aA), "v"(dA[22]) : "memory");
            asm volatile("ds_write_b32 %0, %1 offset:544"
                         :: "v"(aB), "v"(dB[22]) : "memory");
        }

        // 8 k-steps of 32x32x16 (K=16 voxels each). Same-wave DS is in-order:
        // these reads see the writes above. Rows m>=23 read garbage ->
        // pollutes only C rows/cols >=23, never consumed (r9-validated).
        #pragma unroll
        for (int s = 0; s < 8; ++s) {
            h8 Af = *(const h8*)(AimgH + m * RSH + 16 * s + 8 * h);
            h8 Bf = *(const h8*)(BimgH + m * RSH + 16 * s + 8 * h);
            acc = __builtin_amdgcn_mfma_f32_32x32x16_f16(Af, Bf, acc, 0, 0, 0);
        }
    }

    // epilogue: C layout col=lane&31, row=(reg&3)+8*(reg>>2)+4*h (m74/m101)
    float* tile = (float*)wbase;               // reuse wave region
    #pragma unroll
    for (int r = 0; r < 16; ++r) {
        int row = (r & 3) + 8 * (r >> 2) + 4 * h;
        tile[row * 33 + m] = acc[r];
    }
    __syncthreads();
    for (int c = threadIdx.x; c < NCELLS; c += 256) {
        int i = c / NBINS, j = c % NBINS;
        float s = 0.0f;
        #pragma unroll
        for (int w = 0; w < 4; ++w)
            s += ((const float*)(smem + w * WREG))[i * 33 + j];
        partial[((size_t)(b * PBLK + p)) * NCELLS + c] = s;   // coalesced rows
    }
}

// -- K2: fp64 reduction (27x4) + per-batch finalize + grand-final ticket --
__global__ __launch_bounds__(256)
void mi_reduce_batch(const float* __restrict__ partial,
                     double* __restrict__ pab64,
                     int* __restrict__ cnt,       // [5]
                     double* __restrict__ mi_s,   // [4]
                     float* __restrict__ out)
{
    __shared__ double s_pab[NCELLS];
    __shared__ double s_pa[NBINS];
    __shared__ double s_pb[NBINS];
    __shared__ double s_red[4];
    __shared__ int s_last;

    const int g = blockIdx.x;                 // 0..RBLK-1
    const int b = blockIdx.y;
    const int t = threadIdx.x;
    const float* __restrict__ src =
        partial + ((size_t)b * PBLK + (size_t)g * RPB) * NCELLS;

    double a0 = 0.0, a1 = 0.0, a2 = 0.0;
    #pragma unroll
    for (int p = 0; p < RPB; ++p) {
        const float* __restrict__ row = src + (size_t)p * NCELLS;
        a0 += (double)row[t];
        a1 += (double)row[256 + t];
        if (t < NCELLS - 512) a2 += (double)row[512 + t];
    }
    atomicAdd(&pab64[b * NCELLS + t],       a0);   // 27-way contention: cheap
    atomicAdd(&pab64[b * NCELLS + 256 + t], a1);
    if (t < NCELLS - 512) atomicAdd(&pab64[b * NCELLS + 512 + t], a2);

    __syncthreads();
    if (t == 0) {
        __threadfence();
        s_last = (atomicAdd(&cnt[b], 1) == RBLK - 1);
    }
    __syncthreads();
    if (!s_last) return;

    // finalize batch b (529 device-scope loads, one latency round; the 4
    // batch-finalizers run concurrently on different CUs).
    for (int c = t; c < NCELLS; c += 256)
        s_pab[c] = __hip_atomic_load(&pab64[b * NCELLS + c],
                                     __ATOMIC_RELAXED,
                                     __HIP_MEMORY_SCOPE_AGENT)
                   * (1.0 / (double)NVOX);
    __syncthreads();
    if (t < NBINS) {
        double r = 0.0, cl = 0.0;
        for (int j = 0; j < NBINS; ++j) {
            r  += s_pab[t * NBINS + j];
            cl += s_pab[j * NBINS + t];
        }
        s_pa[t] = r; s_pb[t] = cl;
    }
    __syncthreads();
    double tt = 0.0;
    for (int c = t; c < NCELLS; c += 256) {
        double pv   = s_pab[c];
        double papb = s_pa[c / NBINS] * s_pb[c % NBINS];
        tt += pv * log((pv + 1e-7) / (papb + 1e-7) + 1e-7);
    }
    #pragma unroll
    for (int off = 32; off > 0; off >>= 1) tt += __shfl_down(tt, off, 64);
    if ((t & 63) == 0) s_red[t >> 6] = tt;
    __syncthreads();

    if (t == 0) {
        double mi_b = s_red[0] + s_red[1] + s_red[2] + s_red[3];
        __hip_atomic_store(&mi_s[b], mi_b, __ATOMIC_RELEASE,
                           __HIP_MEMORY_SCOPE_AGENT);
        __threadfence();
        if (atomicAdd(&cnt[4], 1) == NBATCH - 1) {
            double m0 = __hip_atomic_load(&mi_s[0], __ATOMIC_RELAXED,
                                          __HIP_MEMORY_SCOPE_AGENT);
            double m1 = __hip_atomic_load(&mi_s[1], __ATOMIC_RELAXED,
                                          __HIP_MEMORY_SCOPE_AGENT);
            double m2 = __hip_atomic_load(&mi_s[2], __ATOMIC_RELAXED,
                                          __HIP_MEMORY_SCOPE_AGENT);
            double m3 = __hip_atomic_load(&mi_s[3], __ATOMIC_RELAXED,
                                          __HIP_MEMORY_SCOPE_AGENT);
            out[0] = (float)(-((m0 + m1) + (m2 + m3)) * 0.25);
        }
    }
}

extern "C" void kernel_launch(void* const* d_in, const int* in_sizes, int n_in,
                              void* d_out, int out_size, void* d_ws, size_t ws_size,
                              hipStream_t stream)
{
    const float* pred = (const float*)d_in[0];
    const float* targ = (const float*)d_in[1];
    float* out = (float*)d_out;
    char* ws = (char*)d_ws;

    // layout: [partial: NBATCH*PBLK*NCELLS f32 = 3.66 MB][pab64: 2116 f64]
    //         [cnt: 5 ints][pad][mi_s: 4 f64]
    const size_t off_pab64 =
        ((size_t)NBATCH * PBLK * NCELLS * 4 + 255) & ~(size_t)255;
    const size_t off_cnt = off_pab64 + (size_t)NBATCH * NCELLS * sizeof(double);
    const size_t off_mi  = (off_cnt + 5 * sizeof(int) + 7) & ~(size_t)7;

    float*  partial = (float*)ws;
    double* pab64   = (double*)(ws + off_pab64);
    int*    cnt     = (int*)(ws + off_cnt);
    double* mi_s    = (double*)(ws + off_mi);

    mi_mfma<<<dim3(PBLK, NBATCH), 256, 0, stream>>>(pred, targ, partial,
                                                    pab64, cnt);
    mi_reduce_batch<<<dim3(RBLK, NBATCH), 256, 0, stream>>>(partial, pab64,
                                                            cnt, mi_s, out);
}

// Round 13
// 101.708 us; speedup vs baseline: 1.0627x; 1.0627x over previous
//
#include <hip/hip_runtime.h>
#include <math.h>

// MutualInformationLoss on MI355X — round 21 (revert to round-19 best, 99.7us).
// r20 post-mortem: packed ds_write2 K1 regressed (+8us): 3.5x VALU + ~140
// live VGPRs + 3 blocks/CU killed the TLP hiding the write->read chains.
// K1 CLOSED at ~43us after 4 falsified redesigns (r12 dirty-row, r16 tr,
// r17/18 tr-pipelined, r20 write2): the r11 scatter kernel's compiler
// schedule + 5 blocks/CU is a robust local optimum at ~70% LDS-pipe duty.
// Structure: K1 = r11 scatter (PBLK=432, 24-row images, 29696B LDS,
// 5 blk/CU); K2 = r19 per-batch finalize (27x4 blocks, per-batch ticket
// -> 4 concurrent 529-cell finalizes, grand ticket sums in fixed order).
// Budget: fill ~44 (harness, fixed) + K1 ~42.9 + downstream ~12.8
// (K2 ~6 + launch gap; O(1728)-block fusion falsified at +76us in r13).

#define NBINS   23
#define NCELLS  529
#define NBATCH  4
#define NVOX    884736
#define PBLK    432               // K1 blocks per batch: 432 * 2048 = 884736
#define RPB     16                // partial rows per reduce block (432/27)
#define RBLK    (PBLK / RPB)      // 27
#define RS      72                // image row stride in halves (144 B)
#define IMGB    (24 * RS * 2)     // 3456 B per image (rows 0..23)
#define WREG    (2 * IMGB)        // 6912 B per wave (A + B images)
#define SMEMB   (4 * WREG + 2048) // 29696 B: guard covers row 24..31 overreads

typedef float    vf4  __attribute__((ext_vector_type(4)));
typedef _Float16 h8   __attribute__((ext_vector_type(8)));
typedef float    f16v __attribute__((ext_vector_type(16)));

#define G1 0.13533528f        // exp(-2)
#define G2 3.3546263e-4f      // exp(-8)
#define G3 1.5229979e-8f      // exp(-18)

// 7-bin window at rows i0..i0+6 via factored Gaussian (2 exp + 1 rcp):
//   w(t) = W0 * R^t * G(t), W0=exp(-968 v^2), R=exp(88 v), v = x - c_mid
__device__ __forceinline__ float window7(float x, int& i0, float* w)
{
    x = fminf(fmaxf(x, 0.0f), 1.0f);
    int ka = (int)floorf(fmaf(x, 22.0f, 0.5f));
    i0 = min(max(ka - 3, 0), 16);
    float v  = fmaf((float)(i0 + 3), -(1.0f / 22.0f), x);
    float W0 = __expf(-968.0f * v * v);
    float R  = __expf(88.0f * v);
    float Ri = __builtin_amdgcn_rcpf(R);
    float R2 = R * R,   R3 = R2 * R;
    float R2i = Ri * Ri, R3i = R2i * Ri;
    w[0] = W0 * (R3i * G3);
    w[1] = W0 * (R2i * G2);
    w[2] = W0 * (Ri  * G1);
    w[3] = W0;
    w[4] = W0 * (R   * G1);
    w[5] = W0 * (R2  * G2);
    w[6] = W0 * (R3  * G3);
    return ((w[0] + w[6]) + (w[1] + w[5])) + ((w[2] + w[4]) + w[3]);
}

// ---------------- K1: fused Parzen-window + MFMA joint histogram ----------------
__global__ __launch_bounds__(256, 5)
void mi_mfma(const float* __restrict__ pred,
             const float* __restrict__ targ,
             float* __restrict__ partial,      // [NBATCH*PBLK][NCELLS]
             double* __restrict__ pab64,       // zeroed here for K2
             int* __restrict__ cnt)            // [5], zeroed here for K2
{
    __shared__ __align__(16) char smem[SMEMB];

    // Block (0,0) zeroes K2's accumulators + counters (replaces memset;
    // K2 runs after K1 completes in stream order, so no race).
    if (blockIdx.x == 0 && blockIdx.y == 0) {
        for (int c = threadIdx.x; c < NBATCH * NCELLS; c += 256)
            pab64[c] = 0.0;
        if (threadIdx.x < 5) cnt[threadIdx.x] = 0;
    }

    const int p    = blockIdx.x;
    const int b    = blockIdx.y;
    const int wv   = threadIdx.x >> 6;
    const int lane = threadIdx.x & 63;
    const int m    = lane & 31;               // bin row for fragment reads
    const int h    = lane >> 5;               // k-half selector

    char* wbase = smem + wv * WREG;
    _Float16* Aimg = (_Float16*)wbase;
    _Float16* Bimg = (_Float16*)(wbase + IMGB);

    const size_t base = (size_t)b * NVOX + (size_t)p * 2048 + (size_t)wv * 512
                      + (size_t)lane * 8;
    const vf4* __restrict__ px4 = (const vf4*)(pred + base);
    const vf4* __restrict__ py4 = (const vf4*)(targ + base);
    vf4 xa = px4[0], xb = px4[1], ya = py4[0], yb = py4[1];
    float xs[8] = {xa.x, xa.y, xa.z, xa.w, xb.x, xb.y, xb.z, xb.w};
    float ys[8] = {ya.x, ya.y, ya.z, ya.w, yb.x, yb.y, yb.z, yb.w};

    f16v acc = {};

    #pragma unroll
    for (int c = 0; c < 8; ++c) {
        // zero rows 0..23 of BOTH images in one contiguous 6912 B span.
        // Rows 24..31 never written; reads of them only pollute C rows/cols
        // >= 23, which are never consumed (validated round 9).
        vf4 z = {0.f, 0.f, 0.f, 0.f};
        #pragma unroll
        for (int it = 0; it < 6; ++it)
            *(vf4*)(wbase + (it * 64 + lane) * 16) = z;
        if (lane < 48)
            *(vf4*)(wbase + (384 + lane) * 16) = z;

        int ia, ja;
        float wa[7], wb[7];
        float sa = window7(xs[c], ia, wa);
        float sb = window7(ys[c], ja, wb);
        float inv = __builtin_amdgcn_rcpf(sa * sb);   // fold both norms onto A

        #pragma unroll
        for (int t = 0; t < 7; ++t) {
            Aimg[(ia + t) * RS + lane] = (_Float16)(wa[t] * inv);  // RNE cvt
            Bimg[(ja + t) * RS + lane] = (_Float16)wb[t];
        }

        // 4 k-steps of 32x32x16 (K=16 voxels each)
        #pragma unroll
        for (int s = 0; s < 4; ++s) {
            h8 Af = *(const h8*)(Aimg + m * RS + 16 * s + 8 * h);
            h8 Bf = *(const h8*)(Bimg + m * RS + 16 * s + 8 * h);
            acc = __builtin_amdgcn_mfma_f32_32x32x16_f16(Af, Bf, acc, 0, 0, 0);
        }
    }

    // epilogue: C layout col=lane&31, row=(reg&3)+8*(reg>>2)+4*h (m74/m101)
    float* tile = (float*)wbase;               // reuse wave region
    #pragma unroll
    for (int r = 0; r < 16; ++r) {
        int row = (r & 3) + 8 * (r >> 2) + 4 * h;
        tile[row * 33 + m] = acc[r];
    }
    __syncthreads();
    for (int c = threadIdx.x; c < NCELLS; c += 256) {
        int i = c / NBINS, j = c % NBINS;
        float s = 0.0f;
        #pragma unroll
        for (int w = 0; w < 4; ++w)
            s += ((const float*)(smem + w * WREG))[i * 33 + j];
        partial[((size_t)(b * PBLK + p)) * NCELLS + c] = s;   // coalesced rows
    }
}

// -- K2: fp64 reduction (27x4) + per-batch finalize + grand-final ticket --
__global__ __launch_bounds__(256)
void mi_reduce_batch(const float* __restrict__ partial,
                     double* __restrict__ pab64,
                     int* __restrict__ cnt,       // [5]
                     double* __restrict__ mi_s,   // [4]
                     float* __restrict__ out)
{
    __shared__ double s_pab[NCELLS];
    __shared__ double s_pa[NBINS];
    __shared__ double s_pb[NBINS];
    __shared__ double s_red[4];
    __shared__ int s_last;

    const int g = blockIdx.x;                 // 0..RBLK-1
    const int b = blockIdx.y;
    const int t = threadIdx.x;
    const float* __restrict__ src =
        partial + ((size_t)b * PBLK + (size_t)g * RPB) * NCELLS;

    double a0 = 0.0, a1 = 0.0, a2 = 0.0;
    #pragma unroll
    for (int p = 0; p < RPB; ++p) {
        const float* __restrict__ row = src + (size_t)p * NCELLS;
        a0 += (double)row[t];
        a1 += (double)row[256 + t];
        if (t < NCELLS - 512) a2 += (double)row[512 + t];
    }
    atomicAdd(&pab64[b * NCELLS + t],       a0);   // 27-way contention: cheap
    atomicAdd(&pab64[b * NCELLS + 256 + t], a1);
    if (t < NCELLS - 512) atomicAdd(&pab64[b * NCELLS + 512 + t], a2);

    // per-batch ticket: __syncthreads drains vmcnt (atomics committed),
    // release fence + counter bump; last block of THIS batch finalizes it.
    __syncthreads();
    if (t == 0) {
        __threadfence();
        s_last = (atomicAdd(&cnt[b], 1) == RBLK - 1);
    }
    __syncthreads();
    if (!s_last) return;

    // finalize batch b (529 device-scope loads, one latency round; the 4
    // batch-finalizers run concurrently on different CUs).
    for (int c = t; c < NCELLS; c += 256)
        s_pab[c] = __hip_atomic_load(&pab64[b * NCELLS + c],
                                     __ATOMIC_RELAXED,
                                     __HIP_MEMORY_SCOPE_AGENT)
                   * (1.0 / (double)NVOX);
    __syncthreads();
    if (t < NBINS) {
        double r = 0.0, cl = 0.0;
        for (int j = 0; j < NBINS; ++j) {
            r  += s_pab[t * NBINS + j];
            cl += s_pab[j * NBINS + t];
        }
        s_pa[t] = r; s_pb[t] = cl;
    }
    __syncthreads();
    double tt = 0.0;
    for (int c = t; c < NCELLS; c += 256) {
        double pv   = s_pab[c];
        double papb = s_pa[c / NBINS] * s_pb[c % NBINS];
        tt += pv * log((pv + 1e-7) / (papb + 1e-7) + 1e-7);
    }
    #pragma unroll
    for (int off = 32; off > 0; off >>= 1) tt += __shfl_down(tt, off, 64);
    if ((t & 63) == 0) s_red[t >> 6] = tt;
    __syncthreads();

    // grand-final ticket: last batch-finalizer sums the 4 mi values in
    // FIXED index order (deterministic) and writes out.
    if (t == 0) {
        double mi_b = s_red[0] + s_red[1] + s_red[2] + s_red[3];
        __hip_atomic_store(&mi_s[b], mi_b, __ATOMIC_RELEASE,
                           __HIP_MEMORY_SCOPE_AGENT);
        __threadfence();
        if (atomicAdd(&cnt[4], 1) == NBATCH - 1) {
            double m0 = __hip_atomic_load(&mi_s[0], __ATOMIC_RELAXED,
                                          __HIP_MEMORY_SCOPE_AGENT);
            double m1 = __hip_atomic_load(&mi_s[1], __ATOMIC_RELAXED,
                                          __HIP_MEMORY_SCOPE_AGENT);
            double m2 = __hip_atomic_load(&mi_s[2], __ATOMIC_RELAXED,
                                          __HIP_MEMORY_SCOPE_AGENT);
            double m3 = __hip_atomic_load(&mi_s[3], __ATOMIC_RELAXED,
                                          __HIP_MEMORY_SCOPE_AGENT);
            out[0] = (float)(-((m0 + m1) + (m2 + m3)) * 0.25);
        }
    }
}

extern "C" void kernel_launch(void* const* d_in, const int* in_sizes, int n_in,
                              void* d_out, int out_size, void* d_ws, size_t ws_size,
                              hipStream_t stream)
{
    const float* pred = (const float*)d_in[0];
    const float* targ = (const float*)d_in[1];
    float* out = (float*)d_out;
    char* ws = (char*)d_ws;

    // layout: [partial: NBATCH*PBLK*NCELLS f32 = 3.66 MB][pab64: 2116 f64]
    //         [cnt: 5 ints][pad][mi_s: 4 f64]
    const size_t off_pab64 =
        ((size_t)NBATCH * PBLK * NCELLS * 4 + 255) & ~(size_t)255;
    const size_t off_cnt = off_pab64 + (size_t)NBATCH * NCELLS * sizeof(double);
    const size_t off_mi  = (off_cnt + 5 * sizeof(int) + 7) & ~(size_t)7;

    float*  partial = (float*)ws;
    double* pab64   = (double*)(ws + off_pab64);
    int*    cnt     = (int*)(ws + off_cnt);
    double* mi_s    = (double*)(ws + off_mi);

    mi_mfma<<<dim3(PBLK, NBATCH), 256, 0, stream>>>(pred, targ, partial,
                                                    pab64, cnt);
    mi_reduce_batch<<<dim3(RBLK, NBATCH), 256, 0, stream>>>(partial, pab64,
                                                            cnt, mi_s, out);
}